// Round 2
// baseline (991.179 us; speedup 1.0000x reference)
//
#include <hip/hip_runtime.h>

typedef unsigned short u16;
typedef unsigned int u32;
typedef __attribute__((ext_vector_type(4))) float f32x4;
typedef __attribute__((ext_vector_type(8))) short bf16x8;   // 8 bf16 bit-patterns (4 VGPRs)
typedef __attribute__((ext_vector_type(8))) u16 u16x8;

#define GLOB_AS __attribute__((address_space(1)))
#define LDS_AS  __attribute__((address_space(3)))

__device__ __forceinline__ void gload_lds16(const void* g, void* l) {
  // async global->LDS, 16B per lane, LDS dest = wave-uniform base + lane*16
  __builtin_amdgcn_global_load_lds((const GLOB_AS void*)g, (LDS_AS void*)l, 16, 0, 0);
}

__device__ __forceinline__ u16 f2bf(float f) {  // RNE float->bf16
  u32 u = __builtin_bit_cast(u32, f);
  u += 0x7fffu + ((u >> 16) & 1u);
  return (u16)(u >> 16);
}

#define MFMA16(a, b, c) __builtin_amdgcn_mfma_f32_16x16x32_bf16(a, b, c, 0, 0, 0)

// ---------------- elementwise cast f32 -> bf16 ----------------
__global__ __launch_bounds__(256) void cast_f32_bf16(const float* __restrict__ s,
                                                     u16* __restrict__ d, int n8) {
  int i = blockIdx.x * 256 + threadIdx.x;
  if (i >= n8) return;
  const f32x4* sp = (const f32x4*)s;
  f32x4 a = sp[2 * i], b = sp[2 * i + 1];
  u16x8 o;
  o[0] = f2bf(a[0]); o[1] = f2bf(a[1]); o[2] = f2bf(a[2]); o[3] = f2bf(a[3]);
  o[4] = f2bf(b[0]); o[5] = f2bf(b[1]); o[6] = f2bf(b[2]); o[7] = f2bf(b[3]);
  ((u16x8*)d)[i] = o;
}

// ---------------- NT GEMM: C[m][n] = sum_k A[m][k]*B[n][k] + bias[n] ----------------
// M=3200, N=K=2048. 128x128 tile, BK=64, 256 thr (4 waves, each a 64x64 sub-tile).
template <int OUTM>  // 0: f32 out, 1: bf16 out
__global__ __launch_bounds__(256) void gemm_nt(const u16* __restrict__ A,
                                               const u16* __restrict__ B,
                                               const float* __restrict__ bias,
                                               void* __restrict__ C) {
  constexpr int K = 2048, N = 2048;
  __shared__ u16 As[128 * 64];
  __shared__ u16 Bs[128 * 64];
  const int tid = threadIdx.x;
  const int wave = tid >> 6, lane = tid & 63;
  const int lg = lane >> 4, li = lane & 15;
  const int m0 = blockIdx.x * 128, n0 = blockIdx.y * 128;
  const int wr = (wave >> 1) * 64, wc = (wave & 1) * 64;

  // staging: wave w stages rows [32w,32w+32) of both tiles, 4 chunks of 8 rows (1KB each)
  const u16* Ag = A + (size_t)(m0 + 32 * wave + (lane >> 3)) * K + (lane & 7) * 8;
  const u16* Bg = B + (size_t)(n0 + 32 * wave + (lane >> 3)) * K + (lane & 7) * 8;
  u16* AsW = As + wave * 2048;
  u16* BsW = Bs + wave * 2048;

  f32x4 acc[4][4] = {};
  for (int k0 = 0; k0 < K; k0 += 64) {
    __syncthreads();  // previous compute done before overwrite
#pragma unroll
    for (int j = 0; j < 4; ++j) {
      gload_lds16(Ag + k0 + (size_t)(8 * j) * K, AsW + j * 512);
      gload_lds16(Bg + k0 + (size_t)(8 * j) * K, BsW + j * 512);
    }
    __syncthreads();  // drains vmcnt -> tiles visible
#pragma unroll
    for (int kk = 0; kk < 64; kk += 32) {
      bf16x8 af[4], bfr[4];
#pragma unroll
      for (int mi = 0; mi < 4; mi++)
        af[mi] = *(const bf16x8*)&As[(wr + mi * 16 + li) * 64 + kk + lg * 8];
#pragma unroll
      for (int ni = 0; ni < 4; ni++)
        bfr[ni] = *(const bf16x8*)&Bs[(wc + ni * 16 + li) * 64 + kk + lg * 8];
#pragma unroll
      for (int mi = 0; mi < 4; mi++)
#pragma unroll
        for (int ni = 0; ni < 4; ni++)
          acc[mi][ni] = MFMA16(af[mi], bfr[ni], acc[mi][ni]);
    }
  }
  float bcol[4];
#pragma unroll
  for (int ni = 0; ni < 4; ni++) bcol[ni] = bias[n0 + wc + ni * 16 + li];
#pragma unroll
  for (int mi = 0; mi < 4; mi++) {
#pragma unroll
    for (int ni = 0; ni < 4; ni++) {
      const int gm = m0 + wr + mi * 16 + lg * 4;
      const int gn = n0 + wc + ni * 16 + li;
#pragma unroll
      for (int r = 0; r < 4; r++) {
        float v = acc[mi][ni][r] + bcol[ni];
        if constexpr (OUTM == 0)
          ((float*)C)[(size_t)(gm + r) * N + gn] = v;
        else
          ((u16*)C)[(size_t)(gm + r) * N + gn] = f2bf(v);
      }
    }
  }
}

// ---------------- fused RMSNorm (over 2048) + 3-axis RoPE, f32 -> bf16 ----------------
__global__ __launch_bounds__(256) void rms_rope(const float* __restrict__ pre,
                                                const float* __restrict__ w,
                                                const float* __restrict__ fcos,
                                                const float* __restrict__ fsin,
                                                u16* __restrict__ out, float fold) {
  const int l = blockIdx.x, tid = threadIdx.x;
  const float* row = pre + (size_t)l * 2048;
  const int d0 = tid * 8;
  f32x4 v0 = *(const f32x4*)(row + d0);
  f32x4 v1 = *(const f32x4*)(row + d0 + 4);
  float ss = v0[0] * v0[0] + v0[1] * v0[1] + v0[2] * v0[2] + v0[3] * v0[3] +
             v1[0] * v1[0] + v1[1] * v1[1] + v1[2] * v1[2] + v1[3] * v1[3];
#pragma unroll
  for (int m = 32; m; m >>= 1) ss += __shfl_xor(ss, m);
  __shared__ float red[4];
  if ((tid & 63) == 0) red[tid >> 6] = ss;
  __syncthreads();
  const float scale =
      rsqrtf((red[0] + red[1] + red[2] + red[3]) * (1.0f / 2048.0f) + 1e-6f) * fold;
  f32x4 w0 = *(const f32x4*)(w + d0);
  f32x4 w1 = *(const f32x4*)(w + d0 + 4);
  float xs[8];
#pragma unroll
  for (int j = 0; j < 4; j++) {
    xs[j] = v0[j] * w0[j] * scale;
    xs[4 + j] = v1[j] * w1[j] * scale;
  }
  const int f = l / 640, rem = l % 640;
  const int hh = rem >> 5, ww = rem & 31;
  const int cb = (d0 & 127) >> 1;  // pair index within the head
  u16x8 ov;
#pragma unroll
  for (int i = 0; i < 4; i++) {
    const int c = cb + i;
    const int prow = c < 22 ? f : (c < 43 ? hh : ww);  // S0=22, S0+S1=43
    const float fc = fcos[prow * 64 + c];
    const float fs = fsin[prow * 64 + c];
    const float xr = xs[2 * i], xi = xs[2 * i + 1];
    ov[2 * i] = f2bf(xr * fc - xi * fs);
    ov[2 * i + 1] = f2bf(xr * fs + xi * fc);
  }
  *(u16x8*)(out + (size_t)l * 2048 + d0) = ov;
}

// ---------------- bf16 transpose [3200][2048] -> [2048][3200] ----------------
__global__ __launch_bounds__(256) void transpose_2d(const u16* __restrict__ src,
                                                    u16* __restrict__ dst) {
  __shared__ u16 t[64][72];
  const int m0 = blockIdx.x * 64, n0 = blockIdx.y * 64;
  const int tid = threadIdx.x;
  const int r = tid >> 3, c8 = (tid & 7) * 8;
#pragma unroll
  for (int j = 0; j < 2; j++) {
    u16x8 v = *(const u16x8*)&src[(size_t)(m0 + r + 32 * j) * 2048 + n0 + c8];
#pragma unroll
    for (int e = 0; e < 8; e++) t[c8 + e][r + 32 * j] = v[e];
  }
  __syncthreads();
#pragma unroll
  for (int j = 0; j < 2; j++) {
    u16x8 v = *(const u16x8*)&t[r + 32 * j][c8];
    *(u16x8*)&dst[(size_t)(n0 + r + 32 * j) * 3200 + m0 + c8] = v;
  }
}

// ---------------- flash attention ----------------
// grid (50, 16): 64 q-rows per block, head = blockIdx.y. 4 waves, each owns 16 q-rows.
// q already folded with log2e/sqrt(128); softmax uses exp2.
__global__ __launch_bounds__(256) void attn_kernel(const u16* __restrict__ Q,
                                                   const u16* __restrict__ Kb,
                                                   const u16* __restrict__ VT,
                                                   u16* __restrict__ O) {
  const int tid = threadIdx.x, wave = tid >> 6, lane = tid & 63;
  const int lg = lane >> 4, li = lane & 15;
  const int h = blockIdx.y;
  const int qrow0 = blockIdx.x * 64 + wave * 16;
  __shared__ float plds[4][16 * 33];  // per-wave P transpose buffer (stride 33 -> 2-way max)
  float* pw = plds[wave];

  bf16x8 qf[4];
  {
    const u16* qb = Q + (size_t)(qrow0 + li) * 2048 + h * 128 + lg * 8;
#pragma unroll
    for (int ks = 0; ks < 4; ks++) qf[ks] = *(const bf16x8*)(qb + ks * 32);
  }
  f32x4 o[8] = {};
  float mrow[4] = {-1e30f, -1e30f, -1e30f, -1e30f};
  float lrow[4] = {0.f, 0.f, 0.f, 0.f};
  const u16* vb = VT + (size_t)(h * 128 + li) * 3200 + lg * 8;

  for (int n0 = 0; n0 < 3200; n0 += 32) {
    f32x4 s0 = {0.f, 0.f, 0.f, 0.f}, s1 = {0.f, 0.f, 0.f, 0.f};
    const u16* kb = Kb + (size_t)(n0 + li) * 2048 + h * 128 + lg * 8;
#pragma unroll
    for (int ks = 0; ks < 4; ks++) {
      bf16x8 k0v = *(const bf16x8*)(kb + ks * 32);
      bf16x8 k1v = *(const bf16x8*)(kb + (size_t)16 * 2048 + ks * 32);
      s0 = MFMA16(qf[ks], k0v, s0);
      s1 = MFMA16(qf[ks], k1v, s1);
    }
    float al[4];
#pragma unroll
    for (int i = 0; i < 4; i++) {
      float pm = fmaxf(s0[i], s1[i]);
      pm = fmaxf(pm, __shfl_xor(pm, 1));
      pm = fmaxf(pm, __shfl_xor(pm, 2));
      pm = fmaxf(pm, __shfl_xor(pm, 4));
      pm = fmaxf(pm, __shfl_xor(pm, 8));
      const float mn = fmaxf(mrow[i], pm);
      al[i] = exp2f(mrow[i] - mn);
      mrow[i] = mn;
      const float p0 = exp2f(s0[i] - mn);
      const float p1 = exp2f(s1[i] - mn);
      lrow[i] = lrow[i] * al[i] + p0 + p1;  // per-lane partial (2 cols); reduced at end
      pw[(lg * 4 + i) * 33 + li] = p0;
      pw[(lg * 4 + i) * 33 + 16 + li] = p1;
    }
#pragma unroll
    for (int f8 = 0; f8 < 8; f8++) {
      o[f8][0] *= al[0]; o[f8][1] *= al[1]; o[f8][2] *= al[2]; o[f8][3] *= al[3];
    }
    // wave-synchronous LDS transpose: writes above, reads below (cross-lane)
    asm volatile("s_waitcnt lgkmcnt(0)" ::: "memory");
    bf16x8 pa;
    {
      const float* pr = &pw[li * 33 + lg * 8];
#pragma unroll
      for (int j = 0; j < 8; j++) pa[j] = (short)f2bf(pr[j]);
    }
#pragma unroll
    for (int f8 = 0; f8 < 8; f8++) {
      bf16x8 vf = *(const bf16x8*)(vb + (size_t)f8 * 16 * 3200 + n0);
      o[f8] = MFMA16(pa, vf, o[f8]);
    }
  }
#pragma unroll
  for (int i = 0; i < 4; i++) {
    float lt = lrow[i];
    lt += __shfl_xor(lt, 1);
    lt += __shfl_xor(lt, 2);
    lt += __shfl_xor(lt, 4);
    lt += __shfl_xor(lt, 8);
    const float inv = 1.0f / lt;
#pragma unroll
    for (int f8 = 0; f8 < 8; f8++)
      O[(size_t)(qrow0 + lg * 4 + i) * 2048 + h * 128 + f8 * 16 + li] =
          f2bf(o[f8][i] * inv);
  }
}

// ---------------- launcher ----------------
extern "C" void kernel_launch(void* const* d_in, const int* in_sizes, int n_in,
                              void* d_out, int out_size, void* d_ws, size_t ws_size,
                              hipStream_t stream) {
  const float* x    = (const float*)d_in[0];
  const float* wq   = (const float*)d_in[1];
  const float* bq   = (const float*)d_in[2];
  const float* wk   = (const float*)d_in[3];
  const float* bk   = (const float*)d_in[4];
  const float* wv   = (const float*)d_in[5];
  const float* bv   = (const float*)d_in[6];
  const float* wo   = (const float*)d_in[7];
  const float* bo   = (const float*)d_in[8];
  const float* nqw  = (const float*)d_in[9];
  const float* nkw  = (const float*)d_in[10];
  const float* fcos = (const float*)d_in[11];
  const float* fsin = (const float*)d_in[12];

  const size_t NEED = 125304832;
  if (ws_size < NEED) return;
  char* ws = (char*)d_ws;
  u16* x_bf   = (u16*)(ws + 0);
  u16* wq_bf  = (u16*)(ws + 13107200);
  u16* wk_bf  = (u16*)(ws + 21495808);
  u16* wv_bf  = (u16*)(ws + 29884416);
  u16* wo_bf  = (u16*)(ws + 38273024);
  float* pre  = (float*)(ws + 46661632);   // 3200*2048 f32; reused as v_bf16 later
  u16* q_bf   = (u16*)(ws + 72876032);
  u16* k_bf   = (u16*)(ws + 85983232);
  u16* vT     = (u16*)(ws + 99090432);     // [2048][3200]
  u16* att_bf = (u16*)(ws + 112197632);

  cast_f32_bf16<<<3200, 256, 0, stream>>>(x, x_bf, 819200);
  cast_f32_bf16<<<2048, 256, 0, stream>>>(wq, wq_bf, 524288);
  cast_f32_bf16<<<2048, 256, 0, stream>>>(wk, wk_bf, 524288);
  cast_f32_bf16<<<2048, 256, 0, stream>>>(wv, wv_bf, 524288);
  cast_f32_bf16<<<2048, 256, 0, stream>>>(wo, wo_bf, 524288);

  const dim3 gg(25, 16);
  const float foldq = 1.4426950408889634f * 0.08838834764831843f;  // log2e / sqrt(128)

  gemm_nt<0><<<gg, 256, 0, stream>>>(x_bf, wq_bf, bq, (void*)pre);
  rms_rope<<<3200, 256, 0, stream>>>(pre, nqw, fcos, fsin, q_bf, foldq);
  gemm_nt<0><<<gg, 256, 0, stream>>>(x_bf, wk_bf, bk, (void*)pre);
  rms_rope<<<3200, 256, 0, stream>>>(pre, nkw, fcos, fsin, k_bf, 1.0f);
  gemm_nt<1><<<gg, 256, 0, stream>>>(x_bf, wv_bf, bv, (void*)pre);  // v bf16 into pre buf
  transpose_2d<<<dim3(50, 32), 256, 0, stream>>>((const u16*)pre, vT);
  attn_kernel<<<dim3(50, 16), 256, 0, stream>>>(q_bf, k_bf, vT, att_bf);
  gemm_nt<0><<<gg, 256, 0, stream>>>(att_bf, wo_bf, bo, d_out);  // f32 out -> d_out
}

// Round 3
// 471.801 us; speedup vs baseline: 2.1008x; 2.1008x over previous
//
#include <hip/hip_runtime.h>

typedef unsigned short u16;
typedef unsigned int u32;
typedef __attribute__((ext_vector_type(4))) float f32x4;
typedef __attribute__((ext_vector_type(8))) short bf16x8;   // 8 bf16 bit-patterns (4 VGPRs)
typedef __attribute__((ext_vector_type(8))) u16 u16x8;

#define GLOB_AS __attribute__((address_space(1)))
#define LDS_AS  __attribute__((address_space(3)))

__device__ __forceinline__ void gload_lds16(const void* g, void* l) {
  // async global->LDS, 16B per lane, LDS dest = wave-uniform base + lane*16
  __builtin_amdgcn_global_load_lds((const GLOB_AS void*)g, (LDS_AS void*)l, 16, 0, 0);
}

__device__ __forceinline__ u16 f2bf(float f) {  // RNE float->bf16
  u32 u = __builtin_bit_cast(u32, f);
  u += 0x7fffu + ((u >> 16) & 1u);
  return (u16)(u >> 16);
}

__device__ __forceinline__ float bf2f(u16 b) {
  u32 u = (u32)b << 16;
  return __builtin_bit_cast(float, u);
}

#define MFMA16(a, b, c) __builtin_amdgcn_mfma_f32_16x16x32_bf16(a, b, c, 0, 0, 0)

// ---------------- elementwise cast f32 -> bf16 ----------------
__global__ __launch_bounds__(256) void cast_f32_bf16(const float* __restrict__ s,
                                                     u16* __restrict__ d, int n8) {
  int i = blockIdx.x * 256 + threadIdx.x;
  if (i >= n8) return;
  const f32x4* sp = (const f32x4*)s;
  f32x4 a = sp[2 * i], b = sp[2 * i + 1];
  u16x8 o;
  o[0] = f2bf(a[0]); o[1] = f2bf(a[1]); o[2] = f2bf(a[2]); o[3] = f2bf(a[3]);
  o[4] = f2bf(b[0]); o[5] = f2bf(b[1]); o[6] = f2bf(b[2]); o[7] = f2bf(b[3]);
  ((u16x8*)d)[i] = o;
}

// ---------------- NT GEMM: C[m][n] = sum_k A[m][k]*B[n][k] + bias[n] ----------------
// M=3200, N=K=2048. 128x128 tile, BK=64, 256 thr (4 waves, each a 64x64 sub-tile).
template <int OUTM>  // 0: f32 out, 1: bf16 out
__global__ __launch_bounds__(256) void gemm_nt(const u16* __restrict__ A,
                                               const u16* __restrict__ B,
                                               const float* __restrict__ bias,
                                               void* __restrict__ C) {
  constexpr int K = 2048, N = 2048;
  __shared__ u16 As[128 * 64];
  __shared__ u16 Bs[128 * 64];
  const int tid = threadIdx.x;
  const int wave = tid >> 6, lane = tid & 63;
  const int lg = lane >> 4, li = lane & 15;
  const int m0 = blockIdx.x * 128, n0 = blockIdx.y * 128;
  const int wr = (wave >> 1) * 64, wc = (wave & 1) * 64;

  // staging: wave w stages rows [32w,32w+32) of both tiles, 4 chunks of 8 rows (1KB each)
  const u16* Ag = A + (size_t)(m0 + 32 * wave + (lane >> 3)) * K + (lane & 7) * 8;
  const u16* Bg = B + (size_t)(n0 + 32 * wave + (lane >> 3)) * K + (lane & 7) * 8;
  u16* AsW = As + wave * 2048;
  u16* BsW = Bs + wave * 2048;

  f32x4 acc[4][4] = {};
  for (int k0 = 0; k0 < K; k0 += 64) {
    __syncthreads();  // previous compute done before overwrite
#pragma unroll
    for (int j = 0; j < 4; ++j) {
      gload_lds16(Ag + k0 + (size_t)(8 * j) * K, AsW + j * 512);
      gload_lds16(Bg + k0 + (size_t)(8 * j) * K, BsW + j * 512);
    }
    __syncthreads();  // drains vmcnt -> tiles visible
#pragma unroll
    for (int kk = 0; kk < 64; kk += 32) {
      bf16x8 af[4], bfr[4];
#pragma unroll
      for (int mi = 0; mi < 4; mi++)
        af[mi] = *(const bf16x8*)&As[(wr + mi * 16 + li) * 64 + kk + lg * 8];
#pragma unroll
      for (int ni = 0; ni < 4; ni++)
        bfr[ni] = *(const bf16x8*)&Bs[(wc + ni * 16 + li) * 64 + kk + lg * 8];
#pragma unroll
      for (int mi = 0; mi < 4; mi++)
#pragma unroll
        for (int ni = 0; ni < 4; ni++)
          acc[mi][ni] = MFMA16(af[mi], bfr[ni], acc[mi][ni]);
    }
  }
  float bcol[4];
#pragma unroll
  for (int ni = 0; ni < 4; ni++) bcol[ni] = bias[n0 + wc + ni * 16 + li];
#pragma unroll
  for (int mi = 0; mi < 4; mi++) {
#pragma unroll
    for (int ni = 0; ni < 4; ni++) {
      const int gm = m0 + wr + mi * 16 + lg * 4;
      const int gn = n0 + wc + ni * 16 + li;
#pragma unroll
      for (int r = 0; r < 4; r++) {
        float v = acc[mi][ni][r] + bcol[ni];
        if constexpr (OUTM == 0)
          ((float*)C)[(size_t)(gm + r) * N + gn] = v;
        else
          ((u16*)C)[(size_t)(gm + r) * N + gn] = f2bf(v);
      }
    }
  }
}

// ---------------- fused RMSNorm (over 2048) + 3-axis RoPE, f32 -> bf16 ----------------
__global__ __launch_bounds__(256) void rms_rope(const float* __restrict__ pre,
                                                const float* __restrict__ w,
                                                const float* __restrict__ fcos,
                                                const float* __restrict__ fsin,
                                                u16* __restrict__ out, float fold) {
  const int l = blockIdx.x, tid = threadIdx.x;
  const float* row = pre + (size_t)l * 2048;
  const int d0 = tid * 8;
  f32x4 v0 = *(const f32x4*)(row + d0);
  f32x4 v1 = *(const f32x4*)(row + d0 + 4);
  float ss = v0[0] * v0[0] + v0[1] * v0[1] + v0[2] * v0[2] + v0[3] * v0[3] +
             v1[0] * v1[0] + v1[1] * v1[1] + v1[2] * v1[2] + v1[3] * v1[3];
#pragma unroll
  for (int m = 32; m; m >>= 1) ss += __shfl_xor(ss, m);
  __shared__ float red[4];
  if ((tid & 63) == 0) red[tid >> 6] = ss;
  __syncthreads();
  const float scale =
      rsqrtf((red[0] + red[1] + red[2] + red[3]) * (1.0f / 2048.0f) + 1e-6f) * fold;
  f32x4 w0 = *(const f32x4*)(w + d0);
  f32x4 w1 = *(const f32x4*)(w + d0 + 4);
  float xs[8];
#pragma unroll
  for (int j = 0; j < 4; j++) {
    xs[j] = v0[j] * w0[j] * scale;
    xs[4 + j] = v1[j] * w1[j] * scale;
  }
  const int f = l / 640, rem = l % 640;
  const int hh = rem >> 5, ww = rem & 31;
  const int cb = (d0 & 127) >> 1;  // pair index within the head
  u16x8 ov;
#pragma unroll
  for (int i = 0; i < 4; i++) {
    const int c = cb + i;
    const int prow = c < 22 ? f : (c < 43 ? hh : ww);  // S0=22, S0+S1=43
    const float fc = fcos[prow * 64 + c];
    const float fs = fsin[prow * 64 + c];
    const float xr = xs[2 * i], xi = xs[2 * i + 1];
    ov[2 * i] = f2bf(xr * fc - xi * fs);
    ov[2 * i + 1] = f2bf(xr * fs + xi * fc);
  }
  *(u16x8*)(out + (size_t)l * 2048 + d0) = ov;
}

// ---------------- bf16 transpose [3200][2048] -> [2048][3200] ----------------
__global__ __launch_bounds__(256) void transpose_2d(const u16* __restrict__ src,
                                                    u16* __restrict__ dst) {
  __shared__ u16 t[64][72];
  const int m0 = blockIdx.x * 64, n0 = blockIdx.y * 64;
  const int tid = threadIdx.x;
  const int r = tid >> 3, c8 = (tid & 7) * 8;
#pragma unroll
  for (int j = 0; j < 2; j++) {
    u16x8 v = *(const u16x8*)&src[(size_t)(m0 + r + 32 * j) * 2048 + n0 + c8];
#pragma unroll
    for (int e = 0; e < 8; e++) t[c8 + e][r + 32 * j] = v[e];
  }
  __syncthreads();
#pragma unroll
  for (int j = 0; j < 2; j++) {
    u16x8 v = *(const u16x8*)&t[r + 32 * j][c8];
    *(u16x8*)&dst[(size_t)(n0 + r + 32 * j) * 3200 + m0 + c8] = v;
  }
}

// ---------------- flash attention, KV-split x2, LDS-staged K/V ----------------
// grid (50, 16, 2): 64 q-rows per block, head = blockIdx.y, kv-split = blockIdx.z.
// 4 waves, each owns 16 q-rows. q pre-folded with log2e/sqrt(128); exp2 domain.
// K tile [32][128] and V^T tile [128][32] staged via global_load_lds with XOR
// source-permute swizzle (linear LDS dest), reads apply the same XOR -> 2-way banks.
__global__ __launch_bounds__(256) void attn_kernel(const u16* __restrict__ Q,
                                                   const u16* __restrict__ Kb,
                                                   const u16* __restrict__ VT,
                                                   u16* __restrict__ Opart,
                                                   float* __restrict__ ml) {
  __shared__ u16 Klds[32 * 128];
  __shared__ u16 Vlds[128 * 32];
  __shared__ float plds[4][16 * 33];  // per-wave P transpose buffer
  const int tid = threadIdx.x, wave = tid >> 6, lane = tid & 63;
  const int lg = lane >> 4, li = lane & 15;
  const int h = blockIdx.y, split = blockIdx.z;
  const int qrow0 = blockIdx.x * 64 + wave * 16;
  float* pw = plds[wave];

  bf16x8 qf[4];
  {
    const u16* qb = Q + (size_t)(qrow0 + li) * 2048 + h * 128 + lg * 8;
#pragma unroll
    for (int ks = 0; ks < 4; ks++) qf[ks] = *(const bf16x8*)(qb + ks * 32);
  }
  f32x4 o[8] = {};
  float mrow[4] = {-1e30f, -1e30f, -1e30f, -1e30f};
  float lrow[4] = {0.f, 0.f, 0.f, 0.f};

  const int vGs = (lane & 7) ^ ((lane >> 3) & 7);  // V source granule (swizzled)

  for (int it = 0; it < 50; ++it) {
    const int n0 = split * 1600 + it * 32;
    __syncthreads();  // previous compute done before overwrite
#pragma unroll
    for (int cc = 0; cc < 2; cc++) {
      const int c = wave * 2 + cc;
      // K: LDS granule (r, g) holds global (r, g ^ (r&7)); dest linear.
      const int kr = c * 4 + (lane >> 4);
      const int kg = (lane & 15) ^ (kr & 7);
      gload_lds16(Kb + (size_t)(n0 + kr) * 2048 + h * 128 + kg * 8,
                  Klds + c * 512 + lane * 8);
      // V^T: within each 128B row-pair, granule G holds global G ^ ((r>>1)&7).
      const int vr = c * 16 + ((lane >> 3) << 1) + (vGs >> 2);
      gload_lds16(VT + (size_t)(h * 128 + vr) * 3200 + n0 + (vGs & 3) * 8,
                  Vlds + c * 512 + lane * 8);
    }
    __syncthreads();  // drains vmcnt -> tiles visible

    f32x4 s0 = {0.f, 0.f, 0.f, 0.f}, s1 = {0.f, 0.f, 0.f, 0.f};
#pragma unroll
    for (int ks = 0; ks < 4; ks++) {
      const int g = (((ks * 4 + lg) ^ (li & 7)) * 8);
      bf16x8 k0 = *(const bf16x8*)&Klds[li * 128 + g];
      bf16x8 k1 = *(const bf16x8*)&Klds[(16 + li) * 128 + g];
      s0 = MFMA16(qf[ks], k0, s0);
      s1 = MFMA16(qf[ks], k1, s1);
    }
    // defer-max (T13): common path skips the shuffle-max chain AND the rescale.
    float need = -1e30f;
#pragma unroll
    for (int i = 0; i < 4; i++)
      need = fmaxf(need, fmaxf(s0[i], s1[i]) - mrow[i]);
    if (__any(need > 8.0f)) {
      float al[4];
#pragma unroll
      for (int i = 0; i < 4; i++) {
        float pm = fmaxf(s0[i], s1[i]);
        pm = fmaxf(pm, __shfl_xor(pm, 1));
        pm = fmaxf(pm, __shfl_xor(pm, 2));
        pm = fmaxf(pm, __shfl_xor(pm, 4));
        pm = fmaxf(pm, __shfl_xor(pm, 8));
        const float mn = fmaxf(mrow[i], pm);
        al[i] = exp2f(mrow[i] - mn);
        mrow[i] = mn;
      }
#pragma unroll
      for (int f8 = 0; f8 < 8; f8++) {
        o[f8][0] *= al[0]; o[f8][1] *= al[1]; o[f8][2] *= al[2]; o[f8][3] *= al[3];
      }
      lrow[0] *= al[0]; lrow[1] *= al[1]; lrow[2] *= al[2]; lrow[3] *= al[3];
    }
#pragma unroll
    for (int i = 0; i < 4; i++) {
      const float p0 = exp2f(s0[i] - mrow[i]);  // bounded by 2^8
      const float p1 = exp2f(s1[i] - mrow[i]);
      lrow[i] += p0 + p1;
      pw[(lg * 4 + i) * 33 + li] = p0;
      pw[(lg * 4 + i) * 33 + 16 + li] = p1;
    }
    // wave-synchronous LDS transpose: writes above, reads below (cross-lane)
    asm volatile("s_waitcnt lgkmcnt(0)" ::: "memory");
    bf16x8 pa;
    {
      const float* pr = &pw[li * 33 + lg * 8];
#pragma unroll
      for (int j = 0; j < 8; j++) pa[j] = (short)f2bf(pr[j]);
    }
    const int Gl = ((li & 1) * 4 + lg) ^ ((li >> 1) & 7);  // swizzled V read granule
#pragma unroll
    for (int f8 = 0; f8 < 8; f8++) {
      bf16x8 vf =
          *(const bf16x8*)&Vlds[(f8 * 16 + (li & ~1) + (Gl >> 2)) * 32 + (Gl & 3) * 8];
      o[f8] = MFMA16(pa, vf, o[f8]);
    }
  }
#pragma unroll
  for (int i = 0; i < 4; i++) {
    float lt = lrow[i];
    lt += __shfl_xor(lt, 1);
    lt += __shfl_xor(lt, 2);
    lt += __shfl_xor(lt, 4);
    lt += __shfl_xor(lt, 8);
    const float inv = 1.0f / lt;
    const int row = qrow0 + lg * 4 + i;
#pragma unroll
    for (int f8 = 0; f8 < 8; f8++)
      Opart[(size_t)split * 6553600 + (size_t)row * 2048 + h * 128 + f8 * 16 + li] =
          f2bf(o[f8][i] * inv);
    if (li == 0) {
      const size_t mlb = ((size_t)(split * 16 + h) * 3200 + row) * 2;
      ml[mlb] = mrow[i];
      ml[mlb + 1] = lt;
    }
  }
}

// ---------------- combine the two KV-split partials ----------------
__global__ __launch_bounds__(256) void attn_combine(const u16* __restrict__ op,
                                                    const float* __restrict__ ml,
                                                    u16* __restrict__ out) {
  const int row = blockIdx.x, tid = threadIdx.x;
  const int c8 = tid * 8, h = c8 >> 7;
  const size_t b0 = ((size_t)h * 3200 + row) * 2;
  const size_t b1 = ((size_t)(16 + h) * 3200 + row) * 2;
  const float m0 = ml[b0], l0 = ml[b0 + 1];
  const float m1 = ml[b1], l1 = ml[b1 + 1];
  const float M = fmaxf(m0, m1);
  const float w0 = exp2f(m0 - M) * l0, w1 = exp2f(m1 - M) * l1;
  const float inv = 1.0f / (w0 + w1);
  u16x8 a = *(const u16x8*)&op[(size_t)row * 2048 + c8];
  u16x8 b = *(const u16x8*)&op[6553600 + (size_t)row * 2048 + c8];
  u16x8 r;
#pragma unroll
  for (int j = 0; j < 8; j++)
    r[j] = f2bf((bf2f(a[j]) * w0 + bf2f(b[j]) * w1) * inv);
  *(u16x8*)&out[(size_t)row * 2048 + c8] = r;
}

// ---------------- launcher ----------------
extern "C" void kernel_launch(void* const* d_in, const int* in_sizes, int n_in,
                              void* d_out, int out_size, void* d_ws, size_t ws_size,
                              hipStream_t stream) {
  const float* x    = (const float*)d_in[0];
  const float* wq   = (const float*)d_in[1];
  const float* bq   = (const float*)d_in[2];
  const float* wk   = (const float*)d_in[3];
  const float* bk   = (const float*)d_in[4];
  const float* wv   = (const float*)d_in[5];
  const float* bv   = (const float*)d_in[6];
  const float* wo   = (const float*)d_in[7];
  const float* bo   = (const float*)d_in[8];
  const float* nqw  = (const float*)d_in[9];
  const float* nkw  = (const float*)d_in[10];
  const float* fcos = (const float*)d_in[11];
  const float* fsin = (const float*)d_in[12];

  const size_t NEED = 125304832;
  if (ws_size < NEED) return;
  char* ws = (char*)d_ws;
  u16* x_bf   = (u16*)(ws + 0);            // dead after V GEMM; ml reuses this region
  u16* wq_bf  = (u16*)(ws + 13107200);
  u16* wk_bf  = (u16*)(ws + 21495808);
  u16* wv_bf  = (u16*)(ws + 29884416);
  u16* wo_bf  = (u16*)(ws + 38273024);
  float* pre  = (float*)(ws + 46661632);   // 3200*2048 f32; reused as o-partials later
  u16* q_bf   = (u16*)(ws + 72876032);
  u16* k_bf   = (u16*)(ws + 85983232);
  u16* vT     = (u16*)(ws + 99090432);     // [2048][3200]
  u16* att_bf = (u16*)(ws + 112197632);
  u16* opart  = (u16*)(ws + 46661632);     // 2 x 3200*2048 bf16 (aliases pre)
  float* ml   = (float*)(ws + 0);          // 2*16*3200*2 f32 (aliases x_bf)

  cast_f32_bf16<<<3200, 256, 0, stream>>>(x, x_bf, 819200);
  cast_f32_bf16<<<2048, 256, 0, stream>>>(wq, wq_bf, 524288);
  cast_f32_bf16<<<2048, 256, 0, stream>>>(wk, wk_bf, 524288);
  cast_f32_bf16<<<2048, 256, 0, stream>>>(wv, wv_bf, 524288);
  cast_f32_bf16<<<2048, 256, 0, stream>>>(wo, wo_bf, 524288);

  const dim3 gg(25, 16);
  const float foldq = 1.4426950408889634f * 0.08838834764831843f;  // log2e / sqrt(128)

  gemm_nt<0><<<gg, 256, 0, stream>>>(x_bf, wq_bf, bq, (void*)pre);
  rms_rope<<<3200, 256, 0, stream>>>(pre, nqw, fcos, fsin, q_bf, foldq);
  gemm_nt<0><<<gg, 256, 0, stream>>>(x_bf, wk_bf, bk, (void*)pre);
  rms_rope<<<3200, 256, 0, stream>>>(pre, nkw, fcos, fsin, k_bf, 1.0f);
  gemm_nt<1><<<gg, 256, 0, stream>>>(x_bf, wv_bf, bv, (void*)pre);  // v bf16 into pre buf
  transpose_2d<<<dim3(50, 32), 256, 0, stream>>>((const u16*)pre, vT);
  attn_kernel<<<dim3(50, 16, 2), 256, 0, stream>>>(q_bf, k_bf, vT, opart, ml);
  attn_combine<<<3200, 256, 0, stream>>>(opart, ml, att_bf);
  gemm_nt<0><<<gg, 256, 0, stream>>>(att_bf, wo_bf, bo, d_out);  // f32 out -> d_out
}

// Round 4
// 453.794 us; speedup vs baseline: 2.1842x; 1.0397x over previous
//
#include <hip/hip_runtime.h>

typedef unsigned short u16;
typedef unsigned int u32;
typedef __attribute__((ext_vector_type(4))) float f32x4;
typedef __attribute__((ext_vector_type(8))) short bf16x8;   // 8 bf16 bit-patterns (4 VGPRs)
typedef __attribute__((ext_vector_type(8))) u16 u16x8;
typedef __attribute__((ext_vector_type(4))) u16 u16x4;

#define GLOB_AS __attribute__((address_space(1)))
#define LDS_AS  __attribute__((address_space(3)))

__device__ __forceinline__ void gload_lds16(const void* g, void* l) {
  // async global->LDS, 16B per lane, LDS dest = wave-uniform base + lane*16
  __builtin_amdgcn_global_load_lds((const GLOB_AS void*)g, (LDS_AS void*)l, 16, 0, 0);
}

__device__ __forceinline__ u16 f2bf(float f) {  // RNE float->bf16
  u32 u = __builtin_bit_cast(u32, f);
  u += 0x7fffu + ((u >> 16) & 1u);
  return (u16)(u >> 16);
}

__device__ __forceinline__ float bf2f(u16 b) {
  u32 u = (u32)b << 16;
  return __builtin_bit_cast(float, u);
}

#define MFMA16(a, b, c) __builtin_amdgcn_mfma_f32_16x16x32_bf16(a, b, c, 0, 0, 0)

// ---------------- elementwise cast f32 -> bf16 ----------------
__global__ __launch_bounds__(256) void cast_f32_bf16(const float* __restrict__ s,
                                                     u16* __restrict__ d, int n8) {
  int i = blockIdx.x * 256 + threadIdx.x;
  if (i >= n8) return;
  const f32x4* sp = (const f32x4*)s;
  f32x4 a = sp[2 * i], b = sp[2 * i + 1];
  u16x8 o;
  o[0] = f2bf(a[0]); o[1] = f2bf(a[1]); o[2] = f2bf(a[2]); o[3] = f2bf(a[3]);
  o[4] = f2bf(b[0]); o[5] = f2bf(b[1]); o[6] = f2bf(b[2]); o[7] = f2bf(b[3]);
  ((u16x8*)d)[i] = o;
}

// ---------------- NT GEMM: C[m][n] = sum_k A[m][k]*B[n][k] + bias[n] ----------------
template <int OUTM>  // 0: f32 out, 1: bf16 out
__global__ __launch_bounds__(256) void gemm_nt(const u16* __restrict__ A,
                                               const u16* __restrict__ B,
                                               const float* __restrict__ bias,
                                               void* __restrict__ C) {
  constexpr int K = 2048, N = 2048;
  __shared__ u16 As[128 * 64];
  __shared__ u16 Bs[128 * 64];
  const int tid = threadIdx.x;
  const int wave = tid >> 6, lane = tid & 63;
  const int lg = lane >> 4, li = lane & 15;
  const int m0 = blockIdx.x * 128, n0 = blockIdx.y * 128;
  const int wr = (wave >> 1) * 64, wc = (wave & 1) * 64;

  const u16* Ag = A + (size_t)(m0 + 32 * wave + (lane >> 3)) * K + (lane & 7) * 8;
  const u16* Bg = B + (size_t)(n0 + 32 * wave + (lane >> 3)) * K + (lane & 7) * 8;
  u16* AsW = As + wave * 2048;
  u16* BsW = Bs + wave * 2048;

  f32x4 acc[4][4] = {};
  for (int k0 = 0; k0 < K; k0 += 64) {
    __syncthreads();
#pragma unroll
    for (int j = 0; j < 4; ++j) {
      gload_lds16(Ag + k0 + (size_t)(8 * j) * K, AsW + j * 512);
      gload_lds16(Bg + k0 + (size_t)(8 * j) * K, BsW + j * 512);
    }
    __syncthreads();
#pragma unroll
    for (int kk = 0; kk < 64; kk += 32) {
      bf16x8 af[4], bfr[4];
#pragma unroll
      for (int mi = 0; mi < 4; mi++)
        af[mi] = *(const bf16x8*)&As[(wr + mi * 16 + li) * 64 + kk + lg * 8];
#pragma unroll
      for (int ni = 0; ni < 4; ni++)
        bfr[ni] = *(const bf16x8*)&Bs[(wc + ni * 16 + li) * 64 + kk + lg * 8];
#pragma unroll
      for (int mi = 0; mi < 4; mi++)
#pragma unroll
        for (int ni = 0; ni < 4; ni++)
          acc[mi][ni] = MFMA16(af[mi], bfr[ni], acc[mi][ni]);
    }
  }
  float bcol[4];
#pragma unroll
  for (int ni = 0; ni < 4; ni++) bcol[ni] = bias[n0 + wc + ni * 16 + li];
#pragma unroll
  for (int mi = 0; mi < 4; mi++) {
#pragma unroll
    for (int ni = 0; ni < 4; ni++) {
      const int gm = m0 + wr + mi * 16 + lg * 4;
      const int gn = n0 + wc + ni * 16 + li;
#pragma unroll
      for (int r = 0; r < 4; r++) {
        float v = acc[mi][ni][r] + bcol[ni];
        if constexpr (OUTM == 0)
          ((float*)C)[(size_t)(gm + r) * N + gn] = v;
        else
          ((u16*)C)[(size_t)(gm + r) * N + gn] = f2bf(v);
      }
    }
  }
}

// ---------------- fused RMSNorm (over 2048) + 3-axis RoPE, f32 -> bf16 ----------------
__global__ __launch_bounds__(256) void rms_rope(const float* __restrict__ pre,
                                                const float* __restrict__ w,
                                                const float* __restrict__ fcos,
                                                const float* __restrict__ fsin,
                                                u16* __restrict__ out, float fold) {
  const int l = blockIdx.x, tid = threadIdx.x;
  const float* row = pre + (size_t)l * 2048;
  const int d0 = tid * 8;
  f32x4 v0 = *(const f32x4*)(row + d0);
  f32x4 v1 = *(const f32x4*)(row + d0 + 4);
  float ss = v0[0] * v0[0] + v0[1] * v0[1] + v0[2] * v0[2] + v0[3] * v0[3] +
             v1[0] * v1[0] + v1[1] * v1[1] + v1[2] * v1[2] + v1[3] * v1[3];
#pragma unroll
  for (int m = 32; m; m >>= 1) ss += __shfl_xor(ss, m);
  __shared__ float red[4];
  if ((tid & 63) == 0) red[tid >> 6] = ss;
  __syncthreads();
  const float scale =
      rsqrtf((red[0] + red[1] + red[2] + red[3]) * (1.0f / 2048.0f) + 1e-6f) * fold;
  f32x4 w0 = *(const f32x4*)(w + d0);
  f32x4 w1 = *(const f32x4*)(w + d0 + 4);
  float xs[8];
#pragma unroll
  for (int j = 0; j < 4; j++) {
    xs[j] = v0[j] * w0[j] * scale;
    xs[4 + j] = v1[j] * w1[j] * scale;
  }
  const int f = l / 640, rem = l % 640;
  const int hh = rem >> 5, ww = rem & 31;
  const int cb = (d0 & 127) >> 1;
  u16x8 ov;
#pragma unroll
  for (int i = 0; i < 4; i++) {
    const int c = cb + i;
    const int prow = c < 22 ? f : (c < 43 ? hh : ww);  // S0=22, S0+S1=43
    const float fc = fcos[prow * 64 + c];
    const float fs = fsin[prow * 64 + c];
    const float xr = xs[2 * i], xi = xs[2 * i + 1];
    ov[2 * i] = f2bf(xr * fc - xi * fs);
    ov[2 * i + 1] = f2bf(xr * fs + xi * fc);
  }
  *(u16x8*)(out + (size_t)l * 2048 + d0) = ov;
}

// ---------------- bf16 transpose [3200][2048] -> [2048][3200] ----------------
__global__ __launch_bounds__(256) void transpose_2d(const u16* __restrict__ src,
                                                    u16* __restrict__ dst) {
  __shared__ u16 t[64][72];
  const int m0 = blockIdx.x * 64, n0 = blockIdx.y * 64;
  const int tid = threadIdx.x;
  const int r = tid >> 3, c8 = (tid & 7) * 8;
#pragma unroll
  for (int j = 0; j < 2; j++) {
    u16x8 v = *(const u16x8*)&src[(size_t)(m0 + r + 32 * j) * 2048 + n0 + c8];
#pragma unroll
    for (int e = 0; e < 8; e++) t[c8 + e][r + 32 * j] = v[e];
  }
  __syncthreads();
#pragma unroll
  for (int j = 0; j < 2; j++) {
    u16x8 v = *(const u16x8*)&t[r + 32 * j][c8];
    *(u16x8*)&dst[(size_t)(n0 + r + 32 * j) * 3200 + m0 + c8] = v;
  }
}

// ---------------- flash attention, KV-split x2, double-buffered LDS K/V ----------------
// grid (50,16,2) remapped so each XCD owns 2 heads (K/V working set 3.2MB < 4MB L2).
// 2-phase pipeline: STAGE(next buf) issued before compute(cur), one vmcnt(0)+barrier/iter.
// P transposed through per-wave bf16 LDS [16][36] (conflict-free writes, 2-way reads).
__global__ __launch_bounds__(256) void attn_kernel(const u16* __restrict__ Q,
                                                   const u16* __restrict__ Kb,
                                                   const u16* __restrict__ VT,
                                                   u16* __restrict__ Opart,
                                                   float* __restrict__ ml) {
  __shared__ u16 Klds[2][32 * 128];
  __shared__ u16 Vlds[2][128 * 32];
  __shared__ u16 plds[4][16 * 36];
  const int tid = threadIdx.x, wave = tid >> 6, lane = tid & 63;
  const int lg = lane >> 4, li = lane & 15;

  // bijective XCD-aware remap: lid = x + 50y + 800z; xcd = lid&7 -> heads {2x,2x+1}
  const int lid = blockIdx.x + 50 * blockIdx.y + 800 * blockIdx.z;
  const int xcd = lid & 7, ixd = lid >> 3;
  const int h = xcd * 2 + (ixd & 1);
  const int rem = ixd >> 1;
  const int split = rem & 1;
  const int qrow0 = (rem >> 1) * 64 + wave * 16;
  const int n0base = split * 1600;

  u16* pw = plds[wave];

  bf16x8 qf[4];
  {
    const u16* qb = Q + (size_t)(qrow0 + li) * 2048 + h * 128 + lg * 8;
#pragma unroll
    for (int ks = 0; ks < 4; ks++) qf[ks] = *(const bf16x8*)(qb + ks * 32);
  }
  f32x4 o[8] = {};
  float mrow[4] = {-1e30f, -1e30f, -1e30f, -1e30f};
  float lrow[4] = {0.f, 0.f, 0.f, 0.f};

  // hoisted per-lane staging pointers (advance by constant per iteration)
  const int kr0 = wave * 8 + (lane >> 4);
  const int kr1 = kr0 + 4;
  const u16* kp0 = Kb + (size_t)(n0base + kr0) * 2048 + h * 128 +
                   ((lane & 15) ^ (kr0 & 7)) * 8;
  const u16* kp1 = Kb + (size_t)(n0base + kr1) * 2048 + h * 128 +
                   ((lane & 15) ^ (kr1 & 7)) * 8;
  const int vGs = (lane & 7) ^ ((lane >> 3) & 7);
  const int vr0 = wave * 32 + ((lane >> 3) << 1) + (vGs >> 2);
  const u16* vp0 = VT + (size_t)(h * 128 + vr0) * 3200 + n0base + (vGs & 3) * 8;
  const int ldsoff = wave * 1024 + lane * 8;  // wave*2*512 + lane*8

#define STAGE(B)                                              \
  do {                                                        \
    gload_lds16(kp0, &Klds[B][0] + ldsoff);                   \
    gload_lds16(kp1, &Klds[B][0] + ldsoff + 512);             \
    gload_lds16(vp0, &Vlds[B][0] + ldsoff);                   \
    gload_lds16(vp0 + 16 * 3200, &Vlds[B][0] + ldsoff + 512); \
    kp0 += 65536;                                             \
    kp1 += 65536;                                             \
    vp0 += 32;                                                \
  } while (0)

  STAGE(0);
  asm volatile("s_waitcnt vmcnt(0)" ::: "memory");
  __syncthreads();

  for (int it = 0; it < 50; ++it) {
    const int buf = it & 1;
    if (it < 49) STAGE(buf ^ 1);  // async prefetch of next tile

    f32x4 s0 = {0.f, 0.f, 0.f, 0.f}, s1 = {0.f, 0.f, 0.f, 0.f};
#pragma unroll
    for (int ks = 0; ks < 4; ks++) {
      const int g = (((ks * 4 + lg) ^ (li & 7)) * 8);
      bf16x8 k0 = *(const bf16x8*)&Klds[buf][li * 128 + g];
      bf16x8 k1 = *(const bf16x8*)&Klds[buf][(16 + li) * 128 + g];
      s0 = MFMA16(qf[ks], k0, s0);
      s1 = MFMA16(qf[ks], k1, s1);
    }
    // defer-max (T13): common path skips the shuffle-max chain AND the rescale.
    float need = -1e30f;
#pragma unroll
    for (int i = 0; i < 4; i++)
      need = fmaxf(need, fmaxf(s0[i], s1[i]) - mrow[i]);
    if (__any(need > 8.0f)) {
      float al[4];
#pragma unroll
      for (int i = 0; i < 4; i++) {
        float pm = fmaxf(s0[i], s1[i]);
        pm = fmaxf(pm, __shfl_xor(pm, 1));
        pm = fmaxf(pm, __shfl_xor(pm, 2));
        pm = fmaxf(pm, __shfl_xor(pm, 4));
        pm = fmaxf(pm, __shfl_xor(pm, 8));
        const float mn = fmaxf(mrow[i], pm);
        al[i] = exp2f(mrow[i] - mn);
        mrow[i] = mn;
      }
#pragma unroll
      for (int f8 = 0; f8 < 8; f8++) {
        o[f8][0] *= al[0]; o[f8][1] *= al[1]; o[f8][2] *= al[2]; o[f8][3] *= al[3];
      }
      lrow[0] *= al[0]; lrow[1] *= al[1]; lrow[2] *= al[2]; lrow[3] *= al[3];
    }
#pragma unroll
    for (int i = 0; i < 4; i++) {
      const float p0 = exp2f(s0[i] - mrow[i]);  // bounded by 2^8
      const float p1 = exp2f(s1[i] - mrow[i]);
      lrow[i] += p0 + p1;
      const int prow = (lg * 4 + i) * 36;
      pw[prow + li] = f2bf(p0);
      pw[prow + 16 + li] = f2bf(p1);
    }
    // wave-synchronous LDS transpose: b16 writes above, b64 reads below (cross-lane)
    asm volatile("s_waitcnt lgkmcnt(0)" ::: "memory");
    bf16x8 pa;
    {
      const u16* pr = &pw[li * 36 + lg * 8];
      u16x4 a0 = *(const u16x4*)pr;
      u16x4 a1 = *(const u16x4*)(pr + 4);
      pa[0] = a0[0]; pa[1] = a0[1]; pa[2] = a0[2]; pa[3] = a0[3];
      pa[4] = a1[0]; pa[5] = a1[1]; pa[6] = a1[2]; pa[7] = a1[3];
    }
    const int Gl = ((li & 1) * 4 + lg) ^ ((li >> 1) & 7);  // swizzled V read granule
#pragma unroll
    for (int f8 = 0; f8 < 8; f8++) {
      bf16x8 vf = *(const bf16x8*)&Vlds[buf][(f8 * 16 + (li & ~1) + (Gl >> 2)) * 32 +
                                            (Gl & 3) * 8];
      o[f8] = MFMA16(pa, vf, o[f8]);
    }
    asm volatile("s_waitcnt vmcnt(0)" ::: "memory");  // next tile landed
    __syncthreads();
  }
#undef STAGE

#pragma unroll
  for (int i = 0; i < 4; i++) {
    float lt = lrow[i];
    lt += __shfl_xor(lt, 1);
    lt += __shfl_xor(lt, 2);
    lt += __shfl_xor(lt, 4);
    lt += __shfl_xor(lt, 8);
    const float inv = 1.0f / lt;
    const int row = qrow0 + lg * 4 + i;
#pragma unroll
    for (int f8 = 0; f8 < 8; f8++)
      Opart[(size_t)split * 6553600 + (size_t)row * 2048 + h * 128 + f8 * 16 + li] =
          f2bf(o[f8][i] * inv);
    if (li == 0) {
      const size_t mlb = ((size_t)(split * 16 + h) * 3200 + row) * 2;
      ml[mlb] = mrow[i];
      ml[mlb + 1] = lt;
    }
  }
}

// ---------------- combine the two KV-split partials ----------------
__global__ __launch_bounds__(256) void attn_combine(const u16* __restrict__ op,
                                                    const float* __restrict__ ml,
                                                    u16* __restrict__ out) {
  const int row = blockIdx.x, tid = threadIdx.x;
  const int c8 = tid * 8, h = c8 >> 7;
  const size_t b0 = ((size_t)h * 3200 + row) * 2;
  const size_t b1 = ((size_t)(16 + h) * 3200 + row) * 2;
  const float m0 = ml[b0], l0 = ml[b0 + 1];
  const float m1 = ml[b1], l1 = ml[b1 + 1];
  const float M = fmaxf(m0, m1);
  const float w0 = exp2f(m0 - M) * l0, w1 = exp2f(m1 - M) * l1;
  const float inv = 1.0f / (w0 + w1);
  u16x8 a = *(const u16x8*)&op[(size_t)row * 2048 + c8];
  u16x8 b = *(const u16x8*)&op[6553600 + (size_t)row * 2048 + c8];
  u16x8 r;
#pragma unroll
  for (int j = 0; j < 8; j++)
    r[j] = f2bf((bf2f(a[j]) * w0 + bf2f(b[j]) * w1) * inv);
  *(u16x8*)&out[(size_t)row * 2048 + c8] = r;
}

// ---------------- launcher ----------------
extern "C" void kernel_launch(void* const* d_in, const int* in_sizes, int n_in,
                              void* d_out, int out_size, void* d_ws, size_t ws_size,
                              hipStream_t stream) {
  const float* x    = (const float*)d_in[0];
  const float* wq   = (const float*)d_in[1];
  const float* bq   = (const float*)d_in[2];
  const float* wk   = (const float*)d_in[3];
  const float* bk   = (const float*)d_in[4];
  const float* wv   = (const float*)d_in[5];
  const float* bv   = (const float*)d_in[6];
  const float* wo   = (const float*)d_in[7];
  const float* bo   = (const float*)d_in[8];
  const float* nqw  = (const float*)d_in[9];
  const float* nkw  = (const float*)d_in[10];
  const float* fcos = (const float*)d_in[11];
  const float* fsin = (const float*)d_in[12];

  const size_t NEED = 125304832;
  if (ws_size < NEED) return;
  char* ws = (char*)d_ws;
  u16* x_bf   = (u16*)(ws + 0);            // dead after V GEMM; ml reuses this region
  u16* wq_bf  = (u16*)(ws + 13107200);
  u16* wk_bf  = (u16*)(ws + 21495808);
  u16* wv_bf  = (u16*)(ws + 29884416);
  u16* wo_bf  = (u16*)(ws + 38273024);
  float* pre  = (float*)(ws + 46661632);   // 3200*2048 f32; reused as o-partials later
  u16* q_bf   = (u16*)(ws + 72876032);
  u16* k_bf   = (u16*)(ws + 85983232);
  u16* vT     = (u16*)(ws + 99090432);     // [2048][3200]
  u16* att_bf = (u16*)(ws + 112197632);
  u16* opart  = (u16*)(ws + 46661632);     // 2 x 3200*2048 bf16 (aliases pre)
  float* ml   = (float*)(ws + 0);          // 2*16*3200*2 f32 (aliases x_bf)

  cast_f32_bf16<<<3200, 256, 0, stream>>>(x, x_bf, 819200);
  cast_f32_bf16<<<2048, 256, 0, stream>>>(wq, wq_bf, 524288);
  cast_f32_bf16<<<2048, 256, 0, stream>>>(wk, wk_bf, 524288);
  cast_f32_bf16<<<2048, 256, 0, stream>>>(wv, wv_bf, 524288);
  cast_f32_bf16<<<2048, 256, 0, stream>>>(wo, wo_bf, 524288);

  const dim3 gg(25, 16);
  const float foldq = 1.4426950408889634f * 0.08838834764831843f;  // log2e / sqrt(128)

  gemm_nt<0><<<gg, 256, 0, stream>>>(x_bf, wq_bf, bq, (void*)pre);
  rms_rope<<<3200, 256, 0, stream>>>(pre, nqw, fcos, fsin, q_bf, foldq);
  gemm_nt<0><<<gg, 256, 0, stream>>>(x_bf, wk_bf, bk, (void*)pre);
  rms_rope<<<3200, 256, 0, stream>>>(pre, nkw, fcos, fsin, k_bf, 1.0f);
  gemm_nt<1><<<gg, 256, 0, stream>>>(x_bf, wv_bf, bv, (void*)pre);  // v bf16 into pre buf
  transpose_2d<<<dim3(50, 32), 256, 0, stream>>>((const u16*)pre, vT);
  attn_kernel<<<dim3(50, 16, 2), 256, 0, stream>>>(q_bf, k_bf, vT, opart, ml);
  attn_combine<<<3200, 256, 0, stream>>>(opart, ml, att_bf);
  gemm_nt<0><<<gg, 256, 0, stream>>>(att_bf, wo_bf, bo, d_out);  // f32 out -> d_out
}